// Round 1
// baseline (58.765 us; speedup 1.0000x reference)
//
#include <hip/hip_runtime.h>
#include <hip/hip_bf16.h>
#include <stdint.h>

// Problem constants (fixed by the reference).
#define M_DIM 8192
#define K_DIM 2048
#define N_DIM 2048
#define NKT   32      // K / 64 tiles along K

typedef __attribute__((ext_vector_type(8))) short bf16x8;
typedef __attribute__((ext_vector_type(4))) float f32x4;

// fp32 -> bf16 round-to-nearest-even (data has no NaNs).
__device__ __forceinline__ ushort f2bf(float f) {
    union { float f; uint32_t u; } v; v.f = f;
    uint32_t u = v.u;
    uint32_t r = u + 0x7fffu + ((u >> 16) & 1u);
    return (ushort)(r >> 16);
}

__global__ void zero_mask(uint32_t* __restrict__ mask) {
    mask[threadIdx.x] = 0u;
}

// One block per 64x64 tile of A: set bit kb of mask[rb] if any element nonzero.
__global__ __launch_bounds__(256) void scan_a(const float* __restrict__ A,
                                              uint32_t* __restrict__ mask) {
    const int tile = blockIdx.x;          // 0..4095
    const int rb = tile >> 5;             // 0..127
    const int kb = tile & 31;             // 0..31
    const int t = threadIdx.x;
    const int r  = t >> 2;                // 0..63 row in tile
    const int cs = (t & 3) << 2;          // float col base
    const float* Ap = A + (size_t)(rb * 64 + r) * K_DIM + kb * 64 + cs;
    bool nz = false;
#pragma unroll
    for (int i = 0; i < 4; ++i) {
        float4 v = *(const float4*)(Ap + i * 16);
        nz = nz || (v.x != 0.f) || (v.y != 0.f) || (v.z != 0.f) || (v.w != 0.f);
    }
    if (__any((int)nz) && (t & 63) == 0) atomicOr(&mask[rb], 1u << kb);
}

// B (fp32, [K][N]) -> Bt (bf16 bits, [N][K]) via LDS transpose, 64x64 tiles.
__global__ __launch_bounds__(256) void conv_bt(const float* __restrict__ B,
                                               ushort* __restrict__ Bt) {
    __shared__ __align__(16) ushort lds[64][72];   // +8 pad keeps 16B align, breaks bank stride
    const int c0 = blockIdx.x * 64;   // N offset
    const int r0 = blockIdx.y * 64;   // K offset
    const int t = threadIdx.x;
    const int r  = t >> 2;
    const int cs = (t & 3) << 2;
#pragma unroll
    for (int i = 0; i < 4; ++i) {
        int c = cs + i * 16;
        float4 v = *(const float4*)(B + (size_t)(r0 + r) * N_DIM + c0 + c);
        lds[r][c + 0] = f2bf(v.x);
        lds[r][c + 1] = f2bf(v.y);
        lds[r][c + 2] = f2bf(v.z);
        lds[r][c + 3] = f2bf(v.w);
    }
    __syncthreads();
    const int ct = t >> 2;            // output row (a column of B), 0..63
    const int s  = (t & 3) * 16;      // k segment
    uint4 tmpv[2];
    ushort* tmp = (ushort*)tmpv;
#pragma unroll
    for (int j = 0; j < 16; ++j) tmp[j] = lds[s + j][ct];
    ushort* dst = Bt + (size_t)(c0 + ct) * K_DIM + r0 + s;
    *(uint4*)(dst)     = tmpv[0];
    *(uint4*)(dst + 8) = tmpv[1];
}

// Block-sparse GEMM: 64x128 C tile per block, 4 waves (2Mx2N), 16x16x32 bf16 MFMA.
// Iterates only nonzero 64-wide K tiles per mask[rb].
__global__ __launch_bounds__(256) void gemm_sparse(const float* __restrict__ A,
                                                   const ushort* __restrict__ Bt,
                                                   const uint32_t* __restrict__ mask,
                                                   float* __restrict__ C) {
    __shared__ __align__(16) ushort smemA[64 * 64];    // 8 KB,  [row 64][k 64] bf16, swizzled
    __shared__ __align__(16) ushort smemB[128 * 64];   // 16 KB, [n 128][k 64]  bf16, swizzled
    char* sA = (char*)smemA;
    char* sB = (char*)smemB;

    const int bid = blockIdx.x;
    const int rb = bid >> 4;      // 0..127 (consecutive blocks share A rows / mask -> L2 reuse)
    const int cb = bid & 15;      // 0..15
    const int tid = threadIdx.x;
    const int lane = tid & 63;
    const int wid = tid >> 6;
    const int wm = wid >> 1;      // 0..1
    const int wn = wid & 1;       // 0..1

    f32x4 acc[2][4];
#pragma unroll
    for (int i = 0; i < 2; ++i)
#pragma unroll
        for (int j = 0; j < 4; ++j) acc[i][j] = (f32x4){0.f, 0.f, 0.f, 0.f};

    uint32_t m = mask[rb];

    // staging thread layout
    const int ar = tid >> 2;            // A row 0..63
    const int ac = (tid & 3) << 2;      // A col base (floats)
    const int br = tid >> 1;            // Bt row (n) 0..127
    const int bseg = (tid & 1) << 6;    // byte offset within 128B row

    while (m) {
        const int kt = __ffs((int)m) - 1;
        m &= (m - 1);

        // ---- stage A tile: fp32 -> bf16, XOR-swizzled ----
        {
            const float* Ap = A + (size_t)(rb * 64 + ar) * K_DIM + kt * 64 + ac;
#pragma unroll
            for (int i = 0; i < 4; ++i) {
                float4 v = *(const float4*)(Ap + i * 16);
                uint32_t lo = (uint32_t)f2bf(v.x) | ((uint32_t)f2bf(v.y) << 16);
                uint32_t hi = (uint32_t)f2bf(v.z) | ((uint32_t)f2bf(v.w) << 16);
                int byte = ar * 128 + (ac + i * 16) * 2;
                byte ^= ((ar & 7) << 4);
                *(uint2*)(sA + byte) = make_uint2(lo, hi);
            }
        }
        // ---- stage Bt tile: already bf16, XOR-swizzled ----
        {
            const char* Bp = (const char*)(Bt + (size_t)(cb * 128 + br) * K_DIM + kt * 64) + bseg;
#pragma unroll
            for (int i = 0; i < 4; ++i) {
                uint4 v = *(const uint4*)(Bp + i * 16);
                int byte = br * 128 + bseg + i * 16;
                byte ^= ((br & 7) << 4);
                *(uint4*)(sB + byte) = v;
            }
        }
        __syncthreads();

#pragma unroll
        for (int ks = 0; ks < 2; ++ks) {
            bf16x8 af[2], bfr[4];
#pragma unroll
            for (int mf = 0; mf < 2; ++mf) {
                int row = wm * 32 + mf * 16 + (lane & 15);
                int byte = row * 128 + (ks * 32 + (lane >> 4) * 8) * 2;
                byte ^= ((row & 7) << 4);
                af[mf] = *(const bf16x8*)(sA + byte);
            }
#pragma unroll
            for (int nf = 0; nf < 4; ++nf) {
                int row = wn * 64 + nf * 16 + (lane & 15);
                int byte = row * 128 + (ks * 32 + (lane >> 4) * 8) * 2;
                byte ^= ((row & 7) << 4);
                bfr[nf] = *(const bf16x8*)(sB + byte);
            }
#pragma unroll
            for (int mf = 0; mf < 2; ++mf)
#pragma unroll
                for (int nf = 0; nf < 4; ++nf)
                    acc[mf][nf] = __builtin_amdgcn_mfma_f32_16x16x32_bf16(
                        af[mf], bfr[nf], acc[mf][nf], 0, 0, 0);
        }
        __syncthreads();
    }

    // ---- epilogue: C/D layout col=lane&15, row=(lane>>4)*4+reg ----
    const int crow0 = rb * 64 + wm * 32 + (lane >> 4) * 4;
    const int ccol0 = cb * 128 + wn * 64 + (lane & 15);
#pragma unroll
    for (int mf = 0; mf < 2; ++mf)
#pragma unroll
        for (int nf = 0; nf < 4; ++nf)
#pragma unroll
            for (int j = 0; j < 4; ++j)
                C[(size_t)(crow0 + mf * 16 + j) * N_DIM + (ccol0 + nf * 16)] = acc[mf][nf][j];
}

extern "C" void kernel_launch(void* const* d_in, const int* in_sizes, int n_in,
                              void* d_out, int out_size, void* d_ws, size_t ws_size,
                              hipStream_t stream) {
    const float* A = (const float*)d_in[0];
    const float* B = (const float*)d_in[1];
    float* C = (float*)d_out;

    // Workspace layout: [0, 8MB) Bt bf16 [N][K]; [8MB, 8MB+512) tile mask (128 x u32)
    ushort* Bt = (ushort*)d_ws;
    uint32_t* mask = (uint32_t*)((char*)d_ws + (size_t)8 * 1024 * 1024);

    zero_mask<<<1, 128, 0, stream>>>(mask);
    scan_a<<<4096, 256, 0, stream>>>(A, mask);
    conv_bt<<<dim3(N_DIM / 64, K_DIM / 64), 256, 0, stream>>>(B, Bt);
    gemm_sparse<<<(M_DIM / 64) * (N_DIM / 128), 256, 0, stream>>>(A, Bt, mask, C);
}

// Round 3
// 52.354 us; speedup vs baseline: 1.1225x; 1.1225x over previous
//
#include <hip/hip_runtime.h>
#include <hip/hip_bf16.h>
#include <stdint.h>

// Problem constants (fixed by the reference).
#define M_DIM 8192
#define K_DIM 2048
#define N_DIM 2048

typedef __attribute__((ext_vector_type(8))) short bf16x8;
typedef __attribute__((ext_vector_type(4))) float f32x4;

// fp32 -> bf16 round-to-nearest-even (data has no NaNs).
__device__ __forceinline__ ushort f2bf(float f) {
    union { float f; uint32_t u; } v; v.f = f;
    uint32_t u = v.u;
    uint32_t r = u + 0x7fffu + ((u >> 16) & 1u);
    return (ushort)(r >> 16);
}

// Fused prep kernel:
//   blocks [0, 512):    scan A -> byte-granular nonzero-tile mask (no atomics, no pre-zero)
//                       block (rb, seg) covers k-tiles seg*8 .. seg*8+7 of row-block rb
//   blocks [512, 1536): convert B (fp32 [K][N]) -> Bt (bf16 [N][K]) via LDS transpose
__global__ __launch_bounds__(256) void prep(const float* __restrict__ A,
                                            const float* __restrict__ B,
                                            ushort* __restrict__ Bt,
                                            uint8_t* __restrict__ maskb) {
    __shared__ __align__(16) ushort lds[64][72];
    const int b = blockIdx.x;
    const int t = threadIdx.x;

    if (b < 512) {
        // ---- scan: 8 k-tiles of one row-block quarter ----
        const int rb = b >> 2;
        const int seg = b & 3;
        const int r  = t >> 2;            // row in tile 0..63
        const int cs = (t & 3) << 2;      // float col base
        const float* base = A + (size_t)(rb * 64 + r) * K_DIM + seg * 512 + cs;
        uint32_t byte = 0;
        for (int it = 0; it < 8; ++it) {
            const float* Ap = base + it * 64;
            bool nz = false;
#pragma unroll
            for (int i = 0; i < 4; ++i) {
                float4 v = *(const float4*)(Ap + i * 16);
                nz = nz || (v.x != 0.f) || (v.y != 0.f) || (v.z != 0.f) || (v.w != 0.f);
            }
            int anynz = __syncthreads_or((int)nz);
            byte |= (anynz ? 1u : 0u) << it;
        }
        if (t == 0) maskb[rb * 4 + seg] = (uint8_t)byte;
    } else {
        // ---- conv: one 64x64 tile of B -> Bt ----
        const int c = b - 512;
        const int c0 = (c & 31) * 64;     // N offset
        const int r0 = (c >> 5) * 64;     // K offset
        const int r  = t >> 2;
        const int cs = (t & 3) << 2;
#pragma unroll
        for (int i = 0; i < 4; ++i) {
            int cc = cs + i * 16;
            float4 v = *(const float4*)(B + (size_t)(r0 + r) * N_DIM + c0 + cc);
            lds[r][cc + 0] = f2bf(v.x);
            lds[r][cc + 1] = f2bf(v.y);
            lds[r][cc + 2] = f2bf(v.z);
            lds[r][cc + 3] = f2bf(v.w);
        }
        __syncthreads();
        const int ct = t >> 2;            // output row (a column of B), 0..63
        const int s  = (t & 3) * 16;      // k segment
        uint4 tmpv[2];
        ushort* tmp = (ushort*)tmpv;
#pragma unroll
        for (int j = 0; j < 16; ++j) tmp[j] = lds[s + j][ct];
        ushort* dst = Bt + (size_t)(c0 + ct) * K_DIM + r0 + s;
        *(uint4*)(dst)     = tmpv[0];
        *(uint4*)(dst + 8) = tmpv[1];
    }
}

// Block-sparse GEMM: 64x128 C tile per block, 4 waves (2Mx2N), 16x16x32 bf16 MFMA.
// Iterates only nonzero 64-wide K tiles per mask[rb]; vectorized epilogue via LDS.
__global__ __launch_bounds__(256) void gemm_sparse(const float* __restrict__ A,
                                                   const ushort* __restrict__ Bt,
                                                   const uint32_t* __restrict__ mask,
                                                   float* __restrict__ C) {
    __shared__ __align__(16) char smem[24576];         // A 8KB | B 16KB ; reused by epilogue
    char* sA = smem;                                    // [row 64][k 64] bf16, swizzled
    char* sB = smem + 8192;                             // [n 128][k 64]  bf16, swizzled

    const int bid = blockIdx.x;
    const int rb = bid >> 4;      // 0..127 (consecutive blocks share A rows / mask -> L2 reuse)
    const int cb = bid & 15;      // 0..15
    const int tid = threadIdx.x;
    const int lane = tid & 63;
    const int wid = tid >> 6;
    const int wm = wid >> 1;      // 0..1
    const int wn = wid & 1;       // 0..1

    f32x4 acc[2][4];
#pragma unroll
    for (int i = 0; i < 2; ++i)
#pragma unroll
        for (int j = 0; j < 4; ++j) acc[i][j] = (f32x4){0.f, 0.f, 0.f, 0.f};

    uint32_t m = mask[rb];

    // staging thread layout
    const int ar = tid >> 2;            // A row 0..63
    const int ac = (tid & 3) << 2;      // A col base (floats)
    const int br = tid >> 1;            // Bt row (n) 0..127
    const int bseg = (tid & 1) << 6;    // byte offset within 128B row

    while (m) {
        const int kt = __ffs((int)m) - 1;
        m &= (m - 1);

        // ---- stage A tile: fp32 -> bf16, XOR-swizzled ----
        {
            const float* Ap = A + (size_t)(rb * 64 + ar) * K_DIM + kt * 64 + ac;
#pragma unroll
            for (int i = 0; i < 4; ++i) {
                float4 v = *(const float4*)(Ap + i * 16);
                uint32_t lo = (uint32_t)f2bf(v.x) | ((uint32_t)f2bf(v.y) << 16);
                uint32_t hi = (uint32_t)f2bf(v.z) | ((uint32_t)f2bf(v.w) << 16);
                int byte = ar * 128 + (ac + i * 16) * 2;
                byte ^= ((ar & 7) << 4);
                *(uint2*)(sA + byte) = make_uint2(lo, hi);
            }
        }
        // ---- stage Bt tile: already bf16, XOR-swizzled ----
        {
            const char* Bp = (const char*)(Bt + (size_t)(cb * 128 + br) * K_DIM + kt * 64) + bseg;
#pragma unroll
            for (int i = 0; i < 4; ++i) {
                uint4 v = *(const uint4*)(Bp + i * 16);
                int byte = br * 128 + bseg + i * 16;
                byte ^= ((br & 7) << 4);
                *(uint4*)(sB + byte) = v;
            }
        }
        __syncthreads();

#pragma unroll
        for (int ks = 0; ks < 2; ++ks) {
            bf16x8 af[2], bfr[4];
#pragma unroll
            for (int mf = 0; mf < 2; ++mf) {
                int row = wm * 32 + mf * 16 + (lane & 15);
                int byte = row * 128 + (ks * 32 + (lane >> 4) * 8) * 2;
                byte ^= ((row & 7) << 4);
                af[mf] = *(const bf16x8*)(sA + byte);
            }
#pragma unroll
            for (int nf = 0; nf < 4; ++nf) {
                int row = wn * 64 + nf * 16 + (lane & 15);
                int byte = row * 128 + (ks * 32 + (lane >> 4) * 8) * 2;
                byte ^= ((row & 7) << 4);
                bfr[nf] = *(const bf16x8*)(sB + byte);
            }
#pragma unroll
            for (int mf = 0; mf < 2; ++mf)
#pragma unroll
                for (int nf = 0; nf < 4; ++nf)
                    acc[mf][nf] = __builtin_amdgcn_mfma_f32_16x16x32_bf16(
                        af[mf], bfr[nf], acc[mf][nf], 0, 0, 0);
        }
        __syncthreads();
    }

    // ---- epilogue: per-wave LDS transpose -> float4 nontemporal stores ----
    // MFMA C/D layout: col=lane&15, row=(lane>>4)*4+reg. Each wave owns a
    // 16x66-float region (4224B); all k-loop LDS reads completed before loop exit,
    // and regions are per-wave, so no extra __syncthreads needed.
    float* ep = (float*)(smem + wid * 4224);
    const int crow_base = rb * 64 + wm * 32;
    const int ccol_base = cb * 128 + wn * 64;
#pragma unroll
    for (int mf = 0; mf < 2; ++mf) {
#pragma unroll
        for (int nf = 0; nf < 4; ++nf)
#pragma unroll
            for (int j = 0; j < 4; ++j)
                ep[((lane >> 4) * 4 + j) * 66 + nf * 16 + (lane & 15)] = acc[mf][nf][j];
#pragma unroll
        for (int rep = 0; rep < 4; ++rep) {
            int row16 = rep * 4 + (lane >> 4);
            f32x4 v = *(const f32x4*)(ep + row16 * 66 + (lane & 15) * 4);
            float* dst = C + (size_t)(crow_base + mf * 16 + row16) * N_DIM
                         + ccol_base + (lane & 15) * 4;
            __builtin_nontemporal_store(v, (f32x4*)dst);
        }
    }
}

extern "C" void kernel_launch(void* const* d_in, const int* in_sizes, int n_in,
                              void* d_out, int out_size, void* d_ws, size_t ws_size,
                              hipStream_t stream) {
    const float* A = (const float*)d_in[0];
    const float* B = (const float*)d_in[1];
    float* C = (float*)d_out;

    // Workspace layout: [0, 8MB) Bt bf16 [N][K]; [8MB, 8MB+512) tile mask (128 x 4 bytes)
    ushort* Bt = (ushort*)d_ws;
    uint8_t* maskb = (uint8_t*)((char*)d_ws + (size_t)8 * 1024 * 1024);

    prep<<<1536, 256, 0, stream>>>(A, B, Bt, maskb);
    gemm_sparse<<<(M_DIM / 64) * (N_DIM / 128), 256, 0, stream>>>(
        A, Bt, (const uint32_t*)maskb, C);
}

// Round 4
// 51.862 us; speedup vs baseline: 1.1331x; 1.0095x over previous
//
#include <hip/hip_runtime.h>
#include <hip/hip_bf16.h>
#include <stdint.h>

// Problem constants (fixed by the reference).
#define M_DIM 8192
#define K_DIM 2048
#define N_DIM 2048

typedef __attribute__((ext_vector_type(8))) short bf16x8;
typedef __attribute__((ext_vector_type(4))) float f32x4;

// fp32 -> bf16 round-to-nearest-even (data has no NaNs).
__device__ __forceinline__ ushort f2bf(float f) {
    union { float f; uint32_t u; } v; v.f = f;
    uint32_t u = v.u;
    uint32_t r = u + 0x7fffu + ((u >> 16) & 1u);
    return (ushort)(r >> 16);
}

typedef const __attribute__((address_space(1))) uint32_t gu32;
typedef __attribute__((address_space(3))) uint32_t lu32;
__device__ __forceinline__ void load_lds16(const void* g, void* l) {
    // 16B per lane, dest = wave-uniform LDS base + lane*16 (HW rule).
    __builtin_amdgcn_global_load_lds((gu32*)g, (lu32*)l, 16, 0, 0);
}

// Fused prep kernel:
//   blocks [0, 512):    scan A -> byte-granular nonzero-tile mask.
//                       One barrier per block: per-thread 8-bit tile mask over
//                       unbarriered loads (full MLP), wave OR-butterfly, LDS combine.
//   blocks [512, 1536): B (fp32 [K][N]) -> Btk: k-tile-major bf16, PRE-SWIZZLED
//                       LDS-image layout: tile(kt) is [n 0..2047][k 0..63],
//                       byte(n,k) = kt*256KB + n*128 + ((k*2) ^ ((n&7)<<4)).
__global__ __launch_bounds__(256) void prep(const float* __restrict__ A,
                                            const float* __restrict__ B,
                                            char* __restrict__ Btk,
                                            uint8_t* __restrict__ maskb) {
    __shared__ __align__(16) ushort lds[64][72];
    const int b = blockIdx.x;
    const int t = threadIdx.x;

    if (b < 512) {
        // ---- scan: 8 k-tiles of one row-block quarter, no inner barriers ----
        const int rb = b >> 2;
        const int seg = b & 3;
        const int r  = t >> 2;            // row in tile 0..63
        const int cs = (t & 3) << 2;      // float col base
        const float* base = A + (size_t)(rb * 64 + r) * K_DIM + seg * 512 + cs;
        uint32_t bits = 0;
#pragma unroll
        for (int it = 0; it < 8; ++it) {
            const float* Ap = base + it * 64;
            bool nz = false;
#pragma unroll
            for (int i = 0; i < 4; ++i) {
                float4 v = *(const float4*)(Ap + i * 16);
                nz = nz || (v.x != 0.f) || (v.y != 0.f) || (v.z != 0.f) || (v.w != 0.f);
            }
            bits |= (nz ? 1u : 0u) << it;
        }
        // bitwise OR across the block: wave butterfly + 4-word LDS combine
        unsigned vv = bits;
#pragma unroll
        for (int off = 1; off < 64; off <<= 1) vv |= __shfl_xor(vv, off);
        volatile uint32_t* red = (volatile uint32_t*)&lds[0][0];
        if ((t & 63) == 0) red[t >> 6] = vv;
        __syncthreads();
        if (t == 0) maskb[rb * 4 + seg] = (uint8_t)(red[0] | red[1] | red[2] | red[3]);
    } else {
        // ---- conv: one 64x64 tile of B -> swizzled k-tile-major image ----
        const int c = b - 512;
        const int c0 = (c & 31) * 64;     // N offset
        const int r0 = (c >> 5) * 64;     // K offset
        const int kt = r0 >> 6;
        const int r  = t >> 2;
        const int cs = (t & 3) << 2;
#pragma unroll
        for (int i = 0; i < 4; ++i) {
            int cc = cs + i * 16;
            float4 v = *(const float4*)(B + (size_t)(r0 + r) * N_DIM + c0 + cc);
            lds[r][cc + 0] = f2bf(v.x);
            lds[r][cc + 1] = f2bf(v.y);
            lds[r][cc + 2] = f2bf(v.z);
            lds[r][cc + 3] = f2bf(v.w);
        }
        __syncthreads();
        const int ct = t >> 2;            // n within tile, 0..63
        const int s  = (t & 3) * 16;      // k segment base
        uint4 tmpv[2];
        ushort* tmp = (ushort*)tmpv;
#pragma unroll
        for (int j = 0; j < 16; ++j) tmp[j] = lds[s + j][ct];
        const int n = c0 + ct;
        char* dst = Btk + (size_t)kt * 262144 + (size_t)n * 128;
        const int sw = (n & 7) << 4;
        *(uint4*)(dst + ((s * 2)      ^ sw)) = tmpv[0];
        *(uint4*)(dst + ((s * 2 + 16) ^ sw)) = tmpv[1];
    }
}

// Block-sparse GEMM: 64x128 C tile per block, 4 waves (2Mx2N), 16x16x32 bf16 MFMA.
// B staged by linear global_load_lds from the pre-swizzled image; A staged via
// reg path (fp32->bf16). XCD-chunked bid swizzle: each XCD owns 2 cb columns,
// so its 1MB of Btk panels stays L2-resident.
__global__ __launch_bounds__(256) void gemm_sparse(const float* __restrict__ A,
                                                   const char* __restrict__ Btk,
                                                   const uint32_t* __restrict__ mask,
                                                   float* __restrict__ C) {
    __shared__ __align__(16) char smem[24576];         // A 8KB | B 16KB ; reused by epilogue
    char* sA = smem;                                    // [row 64][k 64] bf16, swizzled
    char* sB = smem + 8192;                             // [n 128][k 64]  bf16, swizzled

    const int orig = blockIdx.x;
    const int xcd = orig & 7;                 // assumes round-robin wg->XCD; perf-only
    const int i0 = orig >> 3;                 // 0..255
    const int cb = xcd * 2 + (i0 & 1);        // 0..15: fixed pair of cbs per XCD
    const int rb = i0 >> 1;                   // 0..127
    const int tid = threadIdx.x;
    const int lane = tid & 63;
    const int wid = tid >> 6;
    const int wm = wid >> 1;      // 0..1
    const int wn = wid & 1;       // 0..1

    f32x4 acc[2][4];
#pragma unroll
    for (int i = 0; i < 2; ++i)
#pragma unroll
        for (int j = 0; j < 4; ++j) acc[i][j] = (f32x4){0.f, 0.f, 0.f, 0.f};

    uint32_t m = mask[rb];

    // A staging thread layout (reg path)
    const int ar = tid >> 2;            // A row 0..63
    const int ac = (tid & 3) << 2;      // A col base (floats)

    while (m) {
        const int kt = __ffs((int)m) - 1;
        m &= (m - 1);

        // ---- stage B tile: 4 linear global_load_lds (16B/lane) ----
        {
            const char* bt = Btk + (size_t)kt * 262144 + (size_t)cb * 16384;
#pragma unroll
            for (int i = 0; i < 4; ++i) {
                const int chunk = wid * 4 + i;              // 0..15, 1KB each
                load_lds16(bt + chunk * 1024 + lane * 16, sB + chunk * 1024);
            }
        }
        // ---- stage A tile: fp32 -> bf16, XOR-swizzled ----
        {
            const float* Ap = A + (size_t)(rb * 64 + ar) * K_DIM + kt * 64 + ac;
#pragma unroll
            for (int i = 0; i < 4; ++i) {
                float4 v = *(const float4*)(Ap + i * 16);
                uint32_t lo = (uint32_t)f2bf(v.x) | ((uint32_t)f2bf(v.y) << 16);
                uint32_t hi = (uint32_t)f2bf(v.z) | ((uint32_t)f2bf(v.w) << 16);
                int byte = ar * 128 + (ac + i * 16) * 2;
                byte ^= ((ar & 7) << 4);
                *(uint2*)(sA + byte) = make_uint2(lo, hi);
            }
        }
        __syncthreads();

#pragma unroll
        for (int ks = 0; ks < 2; ++ks) {
            bf16x8 af[2], bfr[4];
#pragma unroll
            for (int mf = 0; mf < 2; ++mf) {
                int row = wm * 32 + mf * 16 + (lane & 15);
                int byte = row * 128 + (ks * 32 + (lane >> 4) * 8) * 2;
                byte ^= ((row & 7) << 4);
                af[mf] = *(const bf16x8*)(sA + byte);
            }
#pragma unroll
            for (int nf = 0; nf < 4; ++nf) {
                int row = wn * 64 + nf * 16 + (lane & 15);
                int byte = row * 128 + (ks * 32 + (lane >> 4) * 8) * 2;
                byte ^= ((row & 7) << 4);
                bfr[nf] = *(const bf16x8*)(sB + byte);
            }
#pragma unroll
            for (int mf = 0; mf < 2; ++mf)
#pragma unroll
                for (int nf = 0; nf < 4; ++nf)
                    acc[mf][nf] = __builtin_amdgcn_mfma_f32_16x16x32_bf16(
                        af[mf], bfr[nf], acc[mf][nf], 0, 0, 0);
        }
        __syncthreads();
    }

    // ---- epilogue: per-wave LDS transpose -> f32x4 nontemporal stores ----
    // MFMA C/D layout: col=lane&15, row=(lane>>4)*4+reg. Each wave owns a
    // 16x66-float region (4224B); per-wave regions, no extra barrier needed.
    float* ep = (float*)(smem + wid * 4224);
    const int crow_base = rb * 64 + wm * 32;
    const int ccol_base = cb * 128 + wn * 64;
#pragma unroll
    for (int mf = 0; mf < 2; ++mf) {
#pragma unroll
        for (int nf = 0; nf < 4; ++nf)
#pragma unroll
            for (int j = 0; j < 4; ++j)
                ep[((lane >> 4) * 4 + j) * 66 + nf * 16 + (lane & 15)] = acc[mf][nf][j];
#pragma unroll
        for (int rep = 0; rep < 4; ++rep) {
            int row16 = rep * 4 + (lane >> 4);
            f32x4 v = *(const f32x4*)(ep + row16 * 66 + (lane & 15) * 4);
            float* dst = C + (size_t)(crow_base + mf * 16 + row16) * N_DIM
                         + ccol_base + (lane & 15) * 4;
            __builtin_nontemporal_store(v, (f32x4*)dst);
        }
    }
}

extern "C" void kernel_launch(void* const* d_in, const int* in_sizes, int n_in,
                              void* d_out, int out_size, void* d_ws, size_t ws_size,
                              hipStream_t stream) {
    const float* A = (const float*)d_in[0];
    const float* B = (const float*)d_in[1];
    float* C = (float*)d_out;

    // Workspace: [0, 8MB) Btk swizzled k-tile-major bf16; [8MB, 8MB+512) mask
    char* Btk = (char*)d_ws;
    uint8_t* maskb = (uint8_t*)((char*)d_ws + (size_t)8 * 1024 * 1024);

    prep<<<1536, 256, 0, stream>>>(A, B, Btk, maskb);
    gemm_sparse<<<(M_DIM / 64) * (N_DIM / 128), 256, 0, stream>>>(
        A, Btk, (const uint32_t*)maskb, C);
}

// Round 5
// 41.878 us; speedup vs baseline: 1.4032x; 1.2384x over previous
//
#include <hip/hip_runtime.h>
#include <hip/hip_bf16.h>
#include <stdint.h>

// Problem constants (fixed by the reference).
#define M_DIM 8192
#define K_DIM 2048
#define N_DIM 2048

typedef __attribute__((ext_vector_type(8))) short bf16x8;
typedef __attribute__((ext_vector_type(4))) float f32x4;

// fp32 -> bf16 round-to-nearest-even (data has no NaNs).
__device__ __forceinline__ ushort f2bf(float f) {
    union { float f; uint32_t u; } v; v.f = f;
    uint32_t u = v.u;
    uint32_t r = u + 0x7fffu + ((u >> 16) & 1u);
    return (ushort)(r >> 16);
}

typedef const __attribute__((address_space(1))) uint32_t gu32;
typedef __attribute__((address_space(3))) uint32_t lu32;
__device__ __forceinline__ void load_lds16(const void* g, void* l) {
    // 16B per lane, dest = wave-uniform LDS base + lane*16 (HW rule).
    __builtin_amdgcn_global_load_lds((gu32*)g, (lu32*)l, 16, 0, 0);
}

// Workspace images are byte-for-byte LDS images (XOR-swizzled), so gemm can
// stage them with linear global_load_lds and read fragments conflict-free.
//   A image: per (rb,kt) nonzero tile, 8KB: byte(r,k2) = r*128 + (k2 ^ ((r&7)<<4))
//   B image: per kt, 256KB: byte(n,k2) = n*128 + (k2 ^ ((n&7)<<4))
//
// Fused prep kernel:
//   blocks [0, 512):    scan A (pipelined loads) -> byte mask + packed bf16 A tiles
//   blocks [512, 1536): B (fp32 [K][N]) -> Btk swizzled k-tile-major bf16 image
__global__ __launch_bounds__(256) void prep(const float* __restrict__ A,
                                            const float* __restrict__ B,
                                            char* __restrict__ Btk,
                                            char* __restrict__ Abf,
                                            uint8_t* __restrict__ maskb) {
    __shared__ __align__(16) ushort lds[64][70];   // stride 70 ushort = 35 dw (odd) -> ~2-way max
    const int b = blockIdx.x;
    const int t = threadIdx.x;

    if (b < 512) {
        // ---- scan + pack: 8 k-tiles of one row-block quarter ----
        const int rb = b >> 2;
        const int seg = b & 3;
        const int r  = t >> 2;            // row in tile 0..63
        const int cs = (t & 3) << 2;      // float col base {0,4,8,12}; +i*16
        const float* base = A + (size_t)(rb * 64 + r) * K_DIM + seg * 512 + cs;
        const int sw = (r & 7) << 4;
        uint32_t outb = 0;
        float4 cur[4], nxt[4];
#pragma unroll
        for (int i = 0; i < 4; ++i) cur[i] = *(const float4*)(base + i * 16);
#pragma unroll
        for (int it = 0; it < 8; ++it) {
            if (it < 7) {
#pragma unroll
                for (int i = 0; i < 4; ++i) nxt[i] = *(const float4*)(base + (it + 1) * 64 + i * 16);
            }
            bool nz = false;
#pragma unroll
            for (int i = 0; i < 4; ++i)
                nz = nz || (cur[i].x != 0.f) || (cur[i].y != 0.f) ||
                           (cur[i].z != 0.f) || (cur[i].w != 0.f);
            int anynz = __syncthreads_or((int)nz);
            if (anynz) {
                outb |= 1u << it;
                char* dst = Abf + (size_t)(rb * 32 + seg * 8 + it) * 8192 + r * 128;
#pragma unroll
                for (int i = 0; i < 4; ++i) {
                    uint32_t lo = (uint32_t)f2bf(cur[i].x) | ((uint32_t)f2bf(cur[i].y) << 16);
                    uint32_t hi = (uint32_t)f2bf(cur[i].z) | ((uint32_t)f2bf(cur[i].w) << 16);
                    *(uint2*)(dst + ((cs * 2 + i * 32) ^ sw)) = make_uint2(lo, hi);
                }
            }
#pragma unroll
            for (int i = 0; i < 4; ++i) cur[i] = nxt[i];
        }
        if (t == 0) maskb[rb * 4 + seg] = (uint8_t)outb;
    } else {
        // ---- conv: one 64x64 tile of B -> swizzled k-tile-major image ----
        const int c = b - 512;
        const int c0 = (c & 31) * 64;     // N offset
        const int r0 = (c >> 5) * 64;     // K offset
        const int kt = r0 >> 6;
        const int r  = t >> 2;
        const int cs = (t & 3) << 2;
#pragma unroll
        for (int i = 0; i < 4; ++i) {
            int cc = cs + i * 16;
            float4 v = *(const float4*)(B + (size_t)(r0 + r) * N_DIM + c0 + cc);
            lds[r][cc + 0] = f2bf(v.x);
            lds[r][cc + 1] = f2bf(v.y);
            lds[r][cc + 2] = f2bf(v.z);
            lds[r][cc + 3] = f2bf(v.w);
        }
        __syncthreads();
        const int ct = t >> 2;            // n within tile, 0..63
        const int s  = (t & 3) * 16;      // k segment base
        uint4 tmpv[2];
        ushort* tmp = (ushort*)tmpv;
#pragma unroll
        for (int j = 0; j < 16; ++j) tmp[j] = lds[s + j][ct];
        const int n = c0 + ct;
        char* dst = Btk + (size_t)kt * 262144 + (size_t)n * 128;
        const int swn = (n & 7) << 4;
        *(uint4*)(dst + ((s * 2)      ^ swn)) = tmpv[0];
        *(uint4*)(dst + ((s * 2 + 16) ^ swn)) = tmpv[1];
    }
}

// Block-sparse GEMM: 64x128 C tile per block, 4 waves (2Mx2N), 16x16x32 bf16 MFMA.
// Both operands staged by LINEAR global_load_lds from pre-swizzled images; k-loop
// has zero cvt / ds_write VALU. XCD-chunked cb mapping keeps each XCD's 1MB of
// Btk panels L2-resident.
__global__ __launch_bounds__(256) void gemm_sparse(const char* __restrict__ Abf,
                                                   const char* __restrict__ Btk,
                                                   const uint32_t* __restrict__ mask,
                                                   float* __restrict__ C) {
    __shared__ __align__(16) char smem[24576];         // A 8KB | B 16KB ; reused by epilogue
    char* sA = smem;                                    // [row 64][k 64] bf16, swizzled
    char* sB = smem + 8192;                             // [n 128][k 64]  bf16, swizzled

    const int orig = blockIdx.x;
    const int xcd = orig & 7;                 // assumes round-robin wg->XCD; perf-only
    const int i0 = orig >> 3;                 // 0..255
    const int cb = xcd * 2 + (i0 & 1);        // 0..15: fixed pair of cbs per XCD
    const int rb = i0 >> 1;                   // 0..127
    const int tid = threadIdx.x;
    const int lane = tid & 63;
    const int wid = tid >> 6;
    const int wm = wid >> 1;      // 0..1
    const int wn = wid & 1;       // 0..1

    f32x4 acc[2][4];
#pragma unroll
    for (int i = 0; i < 2; ++i)
#pragma unroll
        for (int j = 0; j < 4; ++j) acc[i][j] = (f32x4){0.f, 0.f, 0.f, 0.f};

    uint32_t m = mask[rb];

    while (m) {
        const int kt = __ffs((int)m) - 1;
        m &= (m - 1);

        // ---- stage B tile: 16KB, 4 linear global_load_lds per thread ----
        {
            const char* bt = Btk + (size_t)kt * 262144 + (size_t)cb * 16384;
#pragma unroll
            for (int i = 0; i < 4; ++i) {
                const int chunk = wid * 4 + i;              // 0..15, 1KB each
                load_lds16(bt + chunk * 1024 + lane * 16, sB + chunk * 1024);
            }
        }
        // ---- stage A tile: 8KB, 2 linear global_load_lds per thread ----
        {
            const char* at = Abf + (size_t)(rb * 32 + kt) * 8192;
#pragma unroll
            for (int i = 0; i < 2; ++i) {
                const int chunk = wid * 2 + i;              // 0..7, 1KB each
                load_lds16(at + chunk * 1024 + lane * 16, sA + chunk * 1024);
            }
        }
        __syncthreads();

#pragma unroll
        for (int ks = 0; ks < 2; ++ks) {
            bf16x8 af[2], bfr[4];
#pragma unroll
            for (int mf = 0; mf < 2; ++mf) {
                int row = wm * 32 + mf * 16 + (lane & 15);
                int byte = row * 128 + (ks * 32 + (lane >> 4) * 8) * 2;
                byte ^= ((row & 7) << 4);
                af[mf] = *(const bf16x8*)(sA + byte);
            }
#pragma unroll
            for (int nf = 0; nf < 4; ++nf) {
                int row = wn * 64 + nf * 16 + (lane & 15);
                int byte = row * 128 + (ks * 32 + (lane >> 4) * 8) * 2;
                byte ^= ((row & 7) << 4);
                bfr[nf] = *(const bf16x8*)(sB + byte);
            }
#pragma unroll
            for (int mf = 0; mf < 2; ++mf)
#pragma unroll
                for (int nf = 0; nf < 4; ++nf)
                    acc[mf][nf] = __builtin_amdgcn_mfma_f32_16x16x32_bf16(
                        af[mf], bfr[nf], acc[mf][nf], 0, 0, 0);
        }
        __syncthreads();
    }

    // ---- epilogue: per-wave LDS transpose -> f32x4 nontemporal stores ----
    // MFMA C/D layout: col=lane&15, row=(lane>>4)*4+reg. Each wave owns a
    // 16x66-float region (4224B); per-wave regions, no extra barrier needed.
    float* ep = (float*)(smem + wid * 4224);
    const int crow_base = rb * 64 + wm * 32;
    const int ccol_base = cb * 128 + wn * 64;
#pragma unroll
    for (int mf = 0; mf < 2; ++mf) {
#pragma unroll
        for (int nf = 0; nf < 4; ++nf)
#pragma unroll
            for (int j = 0; j < 4; ++j)
                ep[((lane >> 4) * 4 + j) * 66 + nf * 16 + (lane & 15)] = acc[mf][nf][j];
#pragma unroll
        for (int rep = 0; rep < 4; ++rep) {
            int row16 = rep * 4 + (lane >> 4);
            f32x4 v = *(const f32x4*)(ep + row16 * 66 + (lane & 15) * 4);
            float* dst = C + (size_t)(crow_base + mf * 16 + row16) * N_DIM
                         + ccol_base + (lane & 15) * 4;
            __builtin_nontemporal_store(v, (f32x4*)dst);
        }
    }
}

extern "C" void kernel_launch(void* const* d_in, const int* in_sizes, int n_in,
                              void* d_out, int out_size, void* d_ws, size_t ws_size,
                              hipStream_t stream) {
    const float* A = (const float*)d_in[0];
    const float* B = (const float*)d_in[1];
    float* C = (float*)d_out;

    // Workspace: [0,8MB) Btk image; [8MB,40MB) Abf images (128*32 tiles * 8KB);
    //            [40MB,+512) mask (128 x 4 bytes)
    char* Btk = (char*)d_ws;
    char* Abf = (char*)d_ws + (size_t)8 * 1024 * 1024;
    uint8_t* maskb = (uint8_t*)((char*)d_ws + (size_t)40 * 1024 * 1024);

    prep<<<1536, 256, 0, stream>>>(A, B, Btk, Abf, maskb);
    gemm_sparse<<<(M_DIM / 64) * (N_DIM / 128), 256, 0, stream>>>(
        Abf, Btk, (const uint32_t*)maskb, C);
}